// Round 15
// baseline (85.250 us; speedup 1.0000x reference)
//
#include <hip/hip_runtime.h>
#include <hip/hip_bf16.h>

// SimpleRNN(tanh) + Dense(5) + softmax, fused. B=8192, T=187, D=1, H=128, C=5.
//
// R15 = R14 (best, 80.0 us) + ONE change: own-fragment-in-register rotation.
// Wave w produces half of fragment Tw=w>>1 (2 packed dwords) -- keep them in
// registers across the barrier; read only the partner half (ds_read_b64) +
// the other 3 fragments (3x ds_read_b128). To keep register assignment
// static (rule #20), U K-tiles are ROTATED per wave: uf_c holds K-tile
// (Tw+c)&3, so "own" is always slot 0; only LDS addresses are runtime.
// g0 assembled with 4 wave-uniform v_cndmask. Read burst -12.5%; chain A's
// first MFMA waits on a b64 (first-issued) instead of a b128.
//
// Carried: x staged in LDS; U,W,b prescaled by 2*log2(e) (tanh = exp2,add,
// rcp,fma); bias rides chain-2's C operand; paired x prefetch (ds_read2);
// reads ordered to match MFMA consumption.
// Structure: 8 waves/block (512 thr), wave w owns rows [16w,16w+16);
// 16-batch tile/block; transposed recurrence h_pre^T = U^T h^T via
// mfma_f32_16x16x32_f16; ONE barrier/step; grid 512 -> 2 blocks/CU.

#define BT 8192
#define TS 187
#define HD 128
#define NC 5

typedef float    f32x4  __attribute__((ext_vector_type(4)));
typedef _Float16 f16x8  __attribute__((ext_vector_type(8)));
typedef __fp16   fp16x2 __attribute__((ext_vector_type(2)));   // cvt_pkrtz return
typedef unsigned int u32;
typedef u32      u32x2  __attribute__((ext_vector_type(2)));

// Prescale: MFMA emits v' = PRE*v; tanh(v) = 1 - 2/(2^v' + 1).
#define PRE 2.885390081777927f

__device__ __forceinline__ float exp2_fast(float v) {
#if __has_builtin(__builtin_amdgcn_exp2f)
    return __builtin_amdgcn_exp2f(v);
#else
    return exp2f(v);
#endif
}

__device__ __forceinline__ float tanh_pre(float vp) {
    float e = exp2_fast(vp);                    // 2^(PRE*v)
    float r = __builtin_amdgcn_rcpf(e + 1.0f);
    return fmaf(-2.0f, r, 1.0f);                // exact at +-inf, no NaN
}

__device__ __forceinline__ u32 pk16(float a, float b) {
    fp16x2 p = __builtin_amdgcn_cvt_pkrtz(a, b);
    return __builtin_bit_cast(u32, p);
}

union frag_u { f16x8 v; u32 w[4]; };

__device__ __forceinline__ void pin_frag(f16x8& f) {
    frag_u pu; pu.v = f;
    asm volatile("" : "+v"(pu.w[0]), "+v"(pu.w[1]), "+v"(pu.w[2]), "+v"(pu.w[3]));
    f = pu.v;
}

__global__ __launch_bounds__(512, 4)
void rnn_fused(const float* __restrict__ xg, const float* __restrict__ wg,
               const float* __restrict__ ug, const float* __restrict__ bg,
               const float* __restrict__ wdg, const float* __restrict__ bdg,
               float* __restrict__ outg)
{
    __shared__ u32   xb[2][4][64][4];   // [dbuf][frag T][lane][dword], 8 KB
    __shared__ float xs[TS][16];        // staged x, ~12 KB
    __shared__ float lg[8][16][NC];     // head partials

    const int tid  = threadIdx.x;
    const int w    = tid >> 6;          // wave 0..7 owns j in [16w, 16w+16)
    const int lane = tid & 63;
    const int l15  = lane & 15;         // batch col / j col for A-frag
    const int l4   = lane >> 4;         // 0..3
    const int b0   = blockIdx.x * 16;   // batch group
    const int Tw   = w >> 1;            // fragment this wave feeds (own = slot 0)
    const int hw   = w & 1;             // which half (dwords 2hw, 2hw+1)
    const int t1   = (Tw + 1) & 3;      // rotated K-tiles
    const int t2   = (Tw + 2) & 3;
    const int t3   = (Tw + 3) & 3;

    // ---- stage x into LDS (one-time, coalesced along time)
    #pragma unroll
    for (int r = 0; r < 6; ++r) {
        const int idx = r * 512 + tid;          // 6*512 = 3072 = 16*192
        const int bb  = idx / 192;              // 0..15
        const int ss  = idx % 192;
        if (ss < TS)
            xs[ss][bb] = xg[(long)(b0 + bb) * TS + ss];
    }

    // ---- U^T fragments (prescaled fp16), K-tiles rotated so own tile = slot 0.
    //   A-frag (M=j, K=i): m = l15 -> j = 16w + l15 ;
    //   elem e -> i = 32*tile + 16(e>>2) + 4l4 + (e&3)
    f16x8 uf0, uf1, uf2, uf3;
    {
        const int j = 16*w + l15;
        #pragma unroll
        for (int e = 0; e < 8; ++e) {
            const int ib = 16*(e>>2) + 4*l4 + (e&3);
            uf0[e] = (_Float16)(PRE * ug[(32*Tw + ib)*HD + j]);
            uf1[e] = (_Float16)(PRE * ug[(32*t1 + ib)*HD + j]);
            uf2[e] = (_Float16)(PRE * ug[(32*t2 + ib)*HD + j]);
            uf3[e] = (_Float16)(PRE * ug[(32*t3 + ib)*HD + j]);
        }
    }
    pin_frag(uf0); pin_frag(uf1); pin_frag(uf2); pin_frag(uf3);

    // ---- per-lane W (prescaled); prescaled b rides chain-2's C operand
    float wv[4]; f32x4 bvv;
    #pragma unroll
    for (int q = 0; q < 4; ++q) {
        const int j = 16*w + 4*l4 + q;
        wv[q]  = PRE * wg[j];
        bvv[q] = PRE * bg[j];
    }

    // ---- precomputed LDS addresses (runtime values, static registers)
    u32*       wp0 = &xb[0][Tw][lane][2*hw];         // own-half write
    u32*       wp1 = &xb[1][Tw][lane][2*hw];
    const u32* pp0 = &xb[0][Tw][lane][2*(1-hw)];     // partner half (b64)
    const u32* pp1 = &xb[1][Tw][lane][2*(1-hw)];
    const u32* r1p0 = &xb[0][t1][lane][0];           // other fragments (b128)
    const u32* r1p1 = &xb[1][t1][lane][0];
    const u32* r2p0 = &xb[0][t2][lane][0];
    const u32* r2p1 = &xb[1][t2][lane][0];
    const u32* r3p0 = &xb[0][t3][lane][0];
    const u32* r3p1 = &xb[1][t3][lane][0];

    // ---- state: g0 = own-tile fragment, g1..g3 rotated; h0 = 0
    f16x8 g0 = (f16x8)(_Float16)0.0f;
    f16x8 g1 = g0, g2 = g0, g3 = g0;

    __syncthreads();                    // xs ready
    float xv = xs[0][l15];

    f32x4 acc;   // post-tanh h persists for the epilogue

    // One step. Own half stays in regs (pk0,pk1); partner half via b64.
    // Read order pr,g2,g1,g3 matches MFMA consumption (lgkmcnt 3/2/1/0).
#define STEP(WP, PP, R1P, R2P, R3P, XNEXT)                                  \
    {                                                                       \
        f32x4 a0, a1;                                                       \
        _Pragma("unroll") for (int q = 0; q < 4; ++q) a0[q] = xv * wv[q];   \
        a0 = __builtin_amdgcn_mfma_f32_16x16x32_f16(uf0, g0, a0,  0, 0, 0); \
        a1 = __builtin_amdgcn_mfma_f32_16x16x32_f16(uf2, g2, bvv, 0, 0, 0); \
        a0 = __builtin_amdgcn_mfma_f32_16x16x32_f16(uf1, g1, a0,  0, 0, 0); \
        a1 = __builtin_amdgcn_mfma_f32_16x16x32_f16(uf3, g3, a1,  0, 0, 0); \
        _Pragma("unroll") for (int q = 0; q < 4; ++q)                       \
            acc[q] = tanh_pre(a0[q] + a1[q]);                               \
        const u32 pk0 = pk16(acc[0], acc[1]);                               \
        const u32 pk1 = pk16(acc[2], acc[3]);                               \
        u32x2 own; own[0] = pk0; own[1] = pk1;                              \
        *(u32x2*)(WP) = own;                                                \
        __syncthreads();                                                    \
        const u32x2 pr = *(const u32x2*)(PP);                               \
        g2 = *(const f16x8*)(R2P);                                          \
        g1 = *(const f16x8*)(R1P);                                          \
        g3 = *(const f16x8*)(R3P);                                          \
        frag_u G;                                                           \
        G.w[0] = hw ? pr[0] : pk0;                                          \
        G.w[1] = hw ? pr[1] : pk1;                                          \
        G.w[2] = hw ? pk0 : pr[0];                                          \
        G.w[3] = hw ? pk1 : pr[1];                                          \
        g0 = G.v;                                                           \
        xv = (XNEXT);                                                       \
    }

    for (int k = 0; k < 93; ++k) {      // steps 0..185 as 93 unrolled pairs
        const float xn1 = xs[2*k + 1][l15];   // paired -> ds_read2_b32
        const float xn2 = xs[2*k + 2][l15];
        STEP(wp0, pp0, r1p0, r2p0, r3p0, xn1);
        STEP(wp1, pp1, r1p1, r2p1, r3p1, xn2);
    }
    STEP(wp0, pp0, r1p0, r2p0, r3p0, 0.0f);   // step 186
#undef STEP

    // ---- head: logits = h @ Wd + bd ; softmax over 5 ----
    float p[NC];
    #pragma unroll
    for (int c = 0; c < NC; ++c) p[c] = 0.0f;
    #pragma unroll
    for (int q = 0; q < 4; ++q) {
        const int j = 16*w + 4*l4 + q;
        #pragma unroll
        for (int c = 0; c < NC; ++c)
            p[c] = fmaf(acc[q], wdg[j*NC + c], p[c]);
    }
    #pragma unroll
    for (int c = 0; c < NC; ++c) {      // reduce over l4 groups
        p[c] += __shfl_xor(p[c], 16, 64);
        p[c] += __shfl_xor(p[c], 32, 64);
    }
    if (l4 == 0) {
        #pragma unroll
        for (int c = 0; c < NC; ++c) lg[w][l15][c] = p[c];
    }
    __syncthreads();

    if (tid < 16) {
        float l[NC];
        #pragma unroll
        for (int c = 0; c < NC; ++c) {
            l[c] = bdg[c];
            #pragma unroll
            for (int ww = 0; ww < 8; ++ww) l[c] += lg[ww][tid][c];
        }
        float m = l[0];
        #pragma unroll
        for (int c = 1; c < NC; ++c) m = fmaxf(m, l[c]);
        float e[NC], ssum = 0.0f;
        #pragma unroll
        for (int c = 0; c < NC; ++c) { e[c] = __expf(l[c] - m); ssum += e[c]; }
        const float rs = 1.0f / ssum;
        #pragma unroll
        for (int c = 0; c < NC; ++c)
            outg[(long)(b0 + tid)*NC + c] = e[c] * rs;
    }
}

extern "C" void kernel_launch(void* const* d_in, const int* in_sizes, int n_in,
                              void* d_out, int out_size, void* d_ws, size_t ws_size,
                              hipStream_t stream) {
    const float* x  = (const float*)d_in[0];  // [8192][187][1]
    const float* W  = (const float*)d_in[1];  // [1][128]
    const float* U  = (const float*)d_in[2];  // [128][128]
    const float* b  = (const float*)d_in[3];  // [128]
    const float* Wd = (const float*)d_in[4];  // [128][5]
    const float* bd = (const float*)d_in[5];  // [5]
    float* out = (float*)d_out;               // [8192][5]

    rnn_fused<<<BT / 16, 512, 0, stream>>>(x, W, U, b, Wd, bd, out);
}

// Round 16
// 79.885 us; speedup vs baseline: 1.0672x; 1.0672x over previous
//
#include <hip/hip_runtime.h>
#include <hip/hip_bf16.h>

// SimpleRNN(tanh) + Dense(5) + softmax, fused. B=8192, T=187, D=1, H=128, C=5.
//
// R16 == R14 restored (best measured: 80.0 us). R15's own-fragment rotation
// regressed (bank conflicts +40% on the stride-16B b64 partner reads) and is
// reverted. This shape is the measured optimum of the structure space:
// 8 waves/block x 512 thr, grid 512 -> 2 blocks/CU = 4 waves/SIMD.
//
// Design (cumulative, each element A/B-validated):
//  - Transposed recurrence h_pre^T = U^T h^T via mfma_f32_16x16x32_f16;
//    D-frag(step s) == B-frag(step s+1) in-lane, so h never needs repacking.
//  - Wave w owns 16 hidden rows; writes half-fragment (T=w>>1, half=w&1) to
//    16B-aligned double-buffered LDS; ONE barrier per step.
//  - x staged in LDS once; paired prefetch (ds_read2_b32) per unrolled pair.
//  - U,W,b prescaled by 2*log2(e): tanh = exp2,add,rcp,fma.
//  - bias rides chain-2's MFMA C operand; two independent depth-2 chains.
//  - Exchange reads ordered h0,h2,h1,h3 to match MFMA consumption.
//  - No dynamic register-array indexing (rule #20); U fragments pinned.

#define BT 8192
#define TS 187
#define HD 128
#define NC 5

typedef float    f32x4  __attribute__((ext_vector_type(4)));
typedef _Float16 f16x8  __attribute__((ext_vector_type(8)));
typedef __fp16   fp16x2 __attribute__((ext_vector_type(2)));   // cvt_pkrtz return
typedef unsigned int u32;
typedef u32      u32x2  __attribute__((ext_vector_type(2)));

// Prescale: MFMA emits v' = PRE*v; tanh(v) = 1 - 2/(2^v' + 1).
#define PRE 2.885390081777927f

__device__ __forceinline__ float exp2_fast(float v) {
#if __has_builtin(__builtin_amdgcn_exp2f)
    return __builtin_amdgcn_exp2f(v);
#else
    return exp2f(v);
#endif
}

__device__ __forceinline__ float tanh_pre(float vp) {
    float e = exp2_fast(vp);                    // 2^(PRE*v)
    float r = __builtin_amdgcn_rcpf(e + 1.0f);
    return fmaf(-2.0f, r, 1.0f);                // exact at +-inf, no NaN
}

__device__ __forceinline__ u32 pk16(float a, float b) {
    fp16x2 p = __builtin_amdgcn_cvt_pkrtz(a, b);
    return __builtin_bit_cast(u32, p);
}

union frag_u { f16x8 v; u32 w[4]; };

__device__ __forceinline__ void pin_frag(f16x8& f) {
    frag_u pu; pu.v = f;
    asm volatile("" : "+v"(pu.w[0]), "+v"(pu.w[1]), "+v"(pu.w[2]), "+v"(pu.w[3]));
    f = pu.v;
}

__global__ __launch_bounds__(512, 4)
void rnn_fused(const float* __restrict__ xg, const float* __restrict__ wg,
               const float* __restrict__ ug, const float* __restrict__ bg,
               const float* __restrict__ wdg, const float* __restrict__ bdg,
               float* __restrict__ outg)
{
    __shared__ u32   xb[2][4][64][4];   // [dbuf][frag T][lane][dword], 8 KB, 16B slots
    __shared__ float xs[TS][16];        // staged x, ~12 KB
    __shared__ float lg[8][16][NC];     // head partials

    const int tid  = threadIdx.x;
    const int w    = tid >> 6;          // wave 0..7 owns j in [16w, 16w+16)
    const int lane = tid & 63;
    const int l15  = lane & 15;         // batch col / j col for A-frag
    const int l4   = lane >> 4;         // 0..3
    const int b0   = blockIdx.x * 16;   // batch group
    const int Tw   = w >> 1;            // fragment this wave feeds
    const int hw   = w & 1;             // which half (dwords 2hw, 2hw+1)

    // ---- stage x into LDS (one-time, coalesced along time)
    #pragma unroll
    for (int r = 0; r < 6; ++r) {
        const int idx = r * 512 + tid;          // 6*512 = 3072 = 16*192
        const int bb  = idx / 192;              // 0..15
        const int ss  = idx % 192;
        if (ss < TS)
            xs[ss][bb] = xg[(long)(b0 + bb) * TS + ss];
    }

    // ---- U^T fragments (prescaled fp16). A-frag (M=j, K=i):
    //   m = l15 -> j = 16w + l15 ; elem e -> i = 32T + 16(e>>2) + 4l4 + (e&3)
    f16x8 uf0, uf1, uf2, uf3;
    {
        const int j = 16*w + l15;
        #pragma unroll
        for (int e = 0; e < 8; ++e) {
            const int i = 16*(e>>2) + 4*l4 + (e&3);
            uf0[e] = (_Float16)(PRE * ug[(i     )*HD + j]);
            uf1[e] = (_Float16)(PRE * ug[(i + 32)*HD + j]);
            uf2[e] = (_Float16)(PRE * ug[(i + 64)*HD + j]);
            uf3[e] = (_Float16)(PRE * ug[(i + 96)*HD + j]);
        }
    }
    pin_frag(uf0); pin_frag(uf1); pin_frag(uf2); pin_frag(uf3);

    // ---- per-lane W (prescaled); prescaled b rides chain-2's C operand
    float wv[4]; f32x4 bvv;
    #pragma unroll
    for (int q = 0; q < 4; ++q) {
        const int j = 16*w + 4*l4 + q;
        wv[q]  = PRE * wg[j];
        bvv[q] = PRE * bg[j];
    }

    // ---- state: h fragments (B layout), h0 = 0
    f16x8 h0 = (f16x8)(_Float16)0.0f;
    f16x8 h1 = h0, h2 = h0, h3 = h0;

    __syncthreads();                    // xs ready
    float xv = xs[0][l15];

    f32x4 acc;   // post-tanh h persists for the epilogue

    // One step; BUF compile-time; XNEXT is a pre-read value (no LDS read here).
    // Reads ordered h0,h2 first: first MFMA pair consumes only those.
#define STEP(BUF, XNEXT)                                                    \
    {                                                                       \
        f32x4 a0, a1;                                                       \
        _Pragma("unroll") for (int q = 0; q < 4; ++q) a0[q] = xv * wv[q];   \
        a0 = __builtin_amdgcn_mfma_f32_16x16x32_f16(uf0, h0, a0,  0, 0, 0); \
        a1 = __builtin_amdgcn_mfma_f32_16x16x32_f16(uf2, h2, bvv, 0, 0, 0); \
        a0 = __builtin_amdgcn_mfma_f32_16x16x32_f16(uf1, h1, a0,  0, 0, 0); \
        a1 = __builtin_amdgcn_mfma_f32_16x16x32_f16(uf3, h3, a1,  0, 0, 0); \
        _Pragma("unroll") for (int q = 0; q < 4; ++q)                       \
            acc[q] = tanh_pre(a0[q] + a1[q]);                               \
        u32x2 pk;                                                           \
        pk[0] = pk16(acc[0], acc[1]);                                       \
        pk[1] = pk16(acc[2], acc[3]);                                       \
        *(u32x2*)&xb[(BUF)][Tw][lane][2*hw] = pk;                           \
        __syncthreads();                                                    \
        h0 = *(const f16x8*)&xb[(BUF)][0][lane][0];                         \
        h2 = *(const f16x8*)&xb[(BUF)][2][lane][0];                         \
        h1 = *(const f16x8*)&xb[(BUF)][1][lane][0];                         \
        h3 = *(const f16x8*)&xb[(BUF)][3][lane][0];                         \
        xv = (XNEXT);                                                       \
    }

    for (int k = 0; k < 93; ++k) {      // steps 0..185 as 93 unrolled pairs
        // both next-x values up front, 64B apart -> single ds_read2_b32,
        // latency decoupled from the step chains below
        const float xn1 = xs[2*k + 1][l15];
        const float xn2 = xs[2*k + 2][l15];
        STEP(0, xn1);
        STEP(1, xn2);
    }
    STEP(0, 0.0f);                      // step 186 (no further x needed)
#undef STEP

    // ---- head: logits = h @ Wd + bd ; softmax over 5 ----
    float p[NC];
    #pragma unroll
    for (int c = 0; c < NC; ++c) p[c] = 0.0f;
    #pragma unroll
    for (int q = 0; q < 4; ++q) {
        const int j = 16*w + 4*l4 + q;
        #pragma unroll
        for (int c = 0; c < NC; ++c)
            p[c] = fmaf(acc[q], wdg[j*NC + c], p[c]);
    }
    #pragma unroll
    for (int c = 0; c < NC; ++c) {      // reduce over l4 groups
        p[c] += __shfl_xor(p[c], 16, 64);
        p[c] += __shfl_xor(p[c], 32, 64);
    }
    if (l4 == 0) {
        #pragma unroll
        for (int c = 0; c < NC; ++c) lg[w][l15][c] = p[c];
    }
    __syncthreads();

    if (tid < 16) {
        float l[NC];
        #pragma unroll
        for (int c = 0; c < NC; ++c) {
            l[c] = bdg[c];
            #pragma unroll
            for (int ww = 0; ww < 8; ++ww) l[c] += lg[ww][tid][c];
        }
        float m = l[0];
        #pragma unroll
        for (int c = 1; c < NC; ++c) m = fmaxf(m, l[c]);
        float e[NC], ssum = 0.0f;
        #pragma unroll
        for (int c = 0; c < NC; ++c) { e[c] = __expf(l[c] - m); ssum += e[c]; }
        const float rs = 1.0f / ssum;
        #pragma unroll
        for (int c = 0; c < NC; ++c)
            outg[(long)(b0 + tid)*NC + c] = e[c] * rs;
    }
}

extern "C" void kernel_launch(void* const* d_in, const int* in_sizes, int n_in,
                              void* d_out, int out_size, void* d_ws, size_t ws_size,
                              hipStream_t stream) {
    const float* x  = (const float*)d_in[0];  // [8192][187][1]
    const float* W  = (const float*)d_in[1];  // [1][128]
    const float* U  = (const float*)d_in[2];  // [128][128]
    const float* b  = (const float*)d_in[3];  // [128]
    const float* Wd = (const float*)d_in[4];  // [128][5]
    const float* bd = (const float*)d_in[5];  // [5]
    float* out = (float*)d_out;               // [8192][5]

    rnn_fused<<<BT / 16, 512, 0, stream>>>(x, W, U, b, Wd, bd, out);
}